// Round 7
// baseline (250.286 us; speedup 1.0000x reference)
//
#include <hip/hip_runtime.h>
#include <hip/hip_bf16.h>

// Problem constants
#define NB     32
#define CIN    256
#define LIN    4096
#define COUT   256
#define KW     9
#define NGRP   4
#define CDIM   128
#define CPG    64          // channels per group (both in and out)
#define LT     128         // l-tile per workgroup
#define NTILE  (LIN / LT)  // 32 tiles per (n,g)
#define NROWS  (LT + 8)    // 136: LT + 2*PAD halo rows
#define RP     68          // LDS row stride in bf16 elems: 136 B (b64-aligned, spreads banks)
#define WF_ELEMS (4*4*9*2*64*8)   // g * co16 * k * chunk * lane * j = 294912

typedef __attribute__((ext_vector_type(8))) short short8;    // 8 bf16 = 4 VGPRs (MFMA operand)
typedef __attribute__((ext_vector_type(4))) short short4v;
typedef __attribute__((ext_vector_type(4))) float float4v;
typedef __attribute__((ext_vector_type(4))) unsigned short ushort4v;

// ---- Pack weights (fp32, [co][ci][k]) into MFMA A-fragment-linear bf16 order ----
// wF[((((g*4+co16)*9+k)*2+chunk)*64+lane)*8 + j] = w[co= g*64+co16*16+(lane&15)][ci= chunk*32+(lane>>4)*8+j][k]
__global__ void pack_weights(const float* __restrict__ w, __hip_bfloat16* __restrict__ wF) {
    int tid = blockIdx.x * blockDim.x + threadIdx.x;
    if (tid >= WF_ELEMS) return;
    int j    = tid & 7;
    int lane = (tid >> 3) & 63;
    int rest = tid >> 9;
    int chunk = rest & 1;  rest >>= 1;
    int k     = rest % 9;  rest /= 9;
    int co16  = rest & 3;
    int g     = rest >> 2;
    int co = g * CPG + co16 * 16 + (lane & 15);
    int ci = chunk * 32 + (lane >> 4) * 8 + j;
    wF[tid] = __float2bfloat16(w[(co * CPG + ci) * KW + k]);
}

// ---- ctx[n][co] = c[n] . c_weight[co] + bias[co] : one wave per output, coalesced ----
__global__ __launch_bounds__(256) void ctx_kernel(const float* __restrict__ c,
                                                  const float* __restrict__ cw,
                                                  const float* __restrict__ bias,
                                                  float* __restrict__ ctxb) {
    int gw   = (blockIdx.x * 256 + threadIdx.x) >> 6;   // wave id: [0, 32*256)
    int lane = threadIdx.x & 63;
    int n  = gw >> 8;
    int co = gw & 255;
    float s = c[n * CDIM + lane]      * cw[co * CDIM + lane]
            + c[n * CDIM + 64 + lane] * cw[co * CDIM + 64 + lane];
    #pragma unroll
    for (int off = 32; off; off >>= 1) s += __shfl_down(s, off);
    if (lane == 0) ctxb[gw] = s + bias[co];
}

// ---- Main: implicit-GEMM grouped conv via bf16 MFMA, register-resident weights ----
// R6 confirmed: removing inner-loop wF global loads took conv ~108 -> ~80 us. Remaining
// gap to the ~40 us HBM floor is phase-convoy duty: stage(~900cyc latency)->barrier->
// compute->store with only 3 blocks/CU overlapping. This version trims peak VGPR to
// <=128 for launch_bounds(256,4) = 4 blocks/CU: halo staging goes from 4xfloat4 on 32
// threads (16 VGPR) to 1xfloat4 on 128 threads (4 VGPR, scalar b16 LDS writes). Peak
// liveness = wreg(72) + v(32) + hv(4) + addr(~16) ~ 124. No cross-phase staging regs
// (the R1/R2 spill trap). Canary: dur_us > 280 => spilled, revert to (256,3).
__global__ __launch_bounds__(256, 4) void conv_mfma(
    const float* __restrict__ x, const __hip_bfloat16* __restrict__ wF,
    const float* __restrict__ ctxb, float* __restrict__ out)
{
    __shared__ unsigned short sx[NROWS * RP];   // [row][ci], row = l_local (l = l0-4+row), 18,496 B
    __shared__ float sctx[CPG];

    const int bx = blockIdx.x;          // 4096 blocks = n(32) * g(4) * tile(32)
    const int t  = bx & 31;
    const int g  = (bx >> 5) & 3;
    const int n  = bx >> 7;
    const int l0 = t * LT;
    const int tid = threadIdx.x;
    const int lane = tid & 63;
    const int wv   = tid >> 6;

    if (tid < CPG) sctx[tid] = ctxb[n * COUT + g * CPG + tid];

    // ---- Weight prefetch: wave wv owns co16 = wv. 18 fragments -> 72 VGPRs, issued
    // first so they ride in flight under the x staging + barrier. Static indexing only. ----
    const short8* wFp = (const short8*)wF;
    const short8* wbase = wFp + (size_t)((g * 4 + wv) * 9 * 2) * 64 + lane;
    short8 wreg[2 * KW];
    #pragma unroll
    for (int i = 0; i < 2 * KW; ++i) wreg[i] = wbase[(size_t)i * 64];

    const float* xb = x + ((size_t)(n * CIN + g * CPG)) * LIN;

    // ---- Stage x: issue ALL global loads first (MLP), then convert + 4x4 transpose + write ----
    const int q4  = 1 + (lane & 15);          // l-quad 1..16 (+16 for i=1) -> rows 4..131
    const int cqb = 4 * wv + (lane >> 4);     // ci-quad 0..15
    float4v v[8];
    #pragma unroll
    for (int i = 0; i < 2; ++i) {
        int lg = l0 - 4 + 4 * (q4 + 16 * i);
        #pragma unroll
        for (int j = 0; j < 4; ++j)
            v[i * 4 + j] = *(const float4v*)(xb + (size_t)(4 * cqb + j) * LIN + lg);
    }
    // Halo rows 0..3 (l0-4..l0-1) and 132..135 (l0+128..l0+131): 128 threads x 1 float4
    // (one ci each, 4 l), block-uniform validity. Only 4 VGPRs of halo state.
    float4v hv = {0.f, 0.f, 0.f, 0.f};
    const int hside = tid >> 6;               // 0=head, 1=tail (valid for tid<128)
    const int hci   = tid & 63;
    if (tid < 128) {
        bool ok = (hside == 0) ? (t > 0) : (t < NTILE - 1);
        int lg  = (hside == 0) ? (l0 - 4) : (l0 + LT);
        if (ok) hv = *(const float4v*)(xb + (size_t)hci * LIN + lg);
    }

    // convert + in-register 4x4 transpose + b64 LDS writes (main rows)
    #pragma unroll
    for (int i = 0; i < 2; ++i) {
        int row = 4 * (q4 + 16 * i);
        #pragma unroll
        for (int d = 0; d < 4; ++d) {
            ushort4v p;
            #pragma unroll
            for (int j = 0; j < 4; ++j)
                p[j] = __builtin_bit_cast(unsigned short, __float2bfloat16(v[i * 4 + j][d]));
            *(ushort4v*)(&sx[(row + d) * RP + 4 * cqb]) = p;
        }
    }
    // halo: 4 scalar b16 writes per thread (64 consecutive ci per row -> conflict-free)
    if (tid < 128) {
        int row0 = (hside == 0) ? 0 : (LT + 4);   // 0 or 132
        #pragma unroll
        for (int d = 0; d < 4; ++d)
            sx[(row0 + d) * RP + hci] = __builtin_bit_cast(unsigned short, __float2bfloat16(hv[d]));
    }
    __syncthreads();

    const int r = lane & 15;
    const int q = lane >> 4;

    float4v acc[LT / 16];           // 8 l16 tiles, one co16 (= wv) each -> 32 regs
    #pragma unroll
    for (int b = 0; b < LT / 16; ++b)
        acc[b] = (float4v){0.f, 0.f, 0.f, 0.f};

    // ---- Pure LDS+MFMA inner loop: no global loads, no vmcnt stalls ----
    #pragma unroll
    for (int k = 0; k < KW; ++k) {
        #pragma unroll
        for (int ch = 0; ch < 2; ++ch) {
            short8 af = wreg[k * 2 + ch];
            #pragma unroll
            for (int l16 = 0; l16 < LT / 16; ++l16) {
                int row = l16 * 16 + r + k;            // out-l + k shift, max 135
                int base = row * RP + ch * 32 + q * 8;
                short4v lo = *(const short4v*)(&sx[base]);
                short4v hi = *(const short4v*)(&sx[base + 4]);
                short8 bf = __builtin_shufflevector(lo, hi, 0, 1, 2, 3, 4, 5, 6, 7);
                acc[l16] = __builtin_amdgcn_mfma_f32_16x16x32_bf16(af, bf, acc[l16], 0, 0, 0);
            }
        }
    }

    // Epilogue: D layout col = lane&15 (l), row = q*4+reg (co-within-16). Wave wv -> co16 = wv.
    float* ob = out + ((size_t)(n * COUT + g * CPG)) * LIN + l0;
    #pragma unroll
    for (int rg = 0; rg < 4; ++rg) {
        int co_l = wv * 16 + q * 4 + rg;
        float add = sctx[co_l];
        #pragma unroll
        for (int l16 = 0; l16 < LT / 16; ++l16)
            ob[(size_t)co_l * LIN + l16 * 16 + r] = acc[l16][rg] + add;
    }
}

extern "C" void kernel_launch(void* const* d_in, const int* in_sizes, int n_in,
                              void* d_out, int out_size, void* d_ws, size_t ws_size,
                              hipStream_t stream) {
    const float* x    = (const float*)d_in[0];   // (32, 256, 4096)
    const float* c    = (const float*)d_in[1];   // (32, 128)
    const float* w    = (const float*)d_in[2];   // (256, 64, 9)
    const float* cw   = (const float*)d_in[3];   // (256, 128)
    const float* bias = (const float*)d_in[4];   // (256,)
    float* out = (float*)d_out;                  // (32, 256, 4096)

    __hip_bfloat16* wF = (__hip_bfloat16*)d_ws;                       // 589,824 B
    float* ctxb = (float*)((char*)d_ws + (size_t)WF_ELEMS * 2);       // 32,768 B

    pack_weights<<<(WF_ELEMS + 255) / 256, 256, 0, stream>>>(w, wF);
    ctx_kernel<<<(NB * COUT * 64) / 256, 256, 0, stream>>>(c, cw, bias, ctxb);
    conv_mfma<<<NB * NGRP * NTILE, 256, 0, stream>>>(x, wF, ctxb, out);
}